// Round 5
// baseline (276.340 us; speedup 1.0000x reference)
//
#include <hip/hip_runtime.h>
#include <math.h>

#define BB 16
#define NN 2048
#define FF 64
#define SS 4
#define PP 22
#define OO 42
#define FPDIM (FF + 2*PP)   // 108

// ---------------- Kernel 1: coords = x@W_s + b_s ; feats = x@W_f + b_f ----------------
__global__ __launch_bounds__(256) void precompute_kernel(
    const float* __restrict__ x, const float* __restrict__ Ws, const float* __restrict__ bs,
    const float* __restrict__ Wf, const float* __restrict__ bf,
    float* __restrict__ coords, float* __restrict__ feats)
{
    int row = blockIdx.x * 256 + threadIdx.x;   // 0 .. B*N-1
    if (row >= BB * NN) return;

    const float4* x4 = (const float4*)(x + (size_t)row * FF);
    float c0 = bs[0], c1 = bs[1], c2 = bs[2], c3 = bs[3];
    float f[PP];
    #pragma unroll
    for (int c = 0; c < PP; c++) f[c] = bf[c];

    #pragma unroll
    for (int k4 = 0; k4 < FF / 4; k4++) {
        float4 xv = x4[k4];
        float xs[4] = {xv.x, xv.y, xv.z, xv.w};
        #pragma unroll
        for (int r = 0; r < 4; r++) {
            int k = k4 * 4 + r;
            float xk = xs[r];
            c0 = fmaf(xk, Ws[k * SS + 0], c0);
            c1 = fmaf(xk, Ws[k * SS + 1], c1);
            c2 = fmaf(xk, Ws[k * SS + 2], c2);
            c3 = fmaf(xk, Ws[k * SS + 3], c3);
            #pragma unroll
            for (int c = 0; c < PP; c++) f[c] = fmaf(xk, Wf[k * PP + c], f[c]);
        }
    }
    float4* cp = (float4*)(coords + (size_t)row * SS);
    *cp = make_float4(c0, c1, c2, c3);
    float* fo = feats + (size_t)row * PP;
    #pragma unroll
    for (int c = 0; c < PP; c++) fo[c] = f[c];
}

// ---------------- Kernel 2: wave-per-query kNN via register counting bisection ----------------
// VGPR budget <= 64 (launch_bounds min 8 waves/EU) so 8 waves/SIMD stay resident;
// distance loop unrolled x4 only, to bound load-landing registers.
__global__ __launch_bounds__(128, 8) void knn_agg_kernel(
    const float* __restrict__ coords, const float* __restrict__ feats,
    const int* __restrict__ nnbr, float* __restrict__ agg)
{
    const int lane = threadIdx.x & 63;
    const int w    = threadIdx.x >> 6;
    const int q    = blockIdx.x * 2 + w;       // 0..32767
    const int b    = q >> 11;
    const int i    = q & (NN - 1);

    int K = *nnbr; K = K < 2 ? 2 : (K > 64 ? 64 : K);

    __shared__ int   selc[2], eqc[2];
    __shared__ int   isel[2][64];
    __shared__ float wsel[2][64];
    __shared__ unsigned long long candk[2][64];   // (d2bits<<32)|j packed keys

    if (lane == 0) { selc[w] = 0; eqc[w] = 0; }

    const float4* cb = (const float4*)(coords + (size_t)b * NN * SS);
    float4 qc = cb[i];

    // ---- distances: all 2048 kept in 32 VGPRs/lane; track per-lane min ----
    float d2r[32];
    float lmin = INFINITY;
    #pragma unroll 4
    for (int r = 0; r < 32; r++) {
        int j = r * 64 + lane;
        float4 c = cb[j];
        float d0 = qc.x - c.x, d1 = qc.y - c.y, d2 = qc.z - c.z, d3 = qc.w - c.w;
        float v = d0 * d0 + d1 * d1 + d2 * d2 + d3 * d3;
        d2r[r] = v;
        lmin = fminf(lmin, v);
    }

    // ---- first-probe estimator: mean of per-lane minima ~ K/N quantile ----
    float s = lmin;
    #pragma unroll
    for (int off = 1; off < 64; off <<= 1) s += __shfl_xor(s, off, 64);
    float t0 = s * (1.0f / 64.0f);

    // ---- bisection on the threshold: invariant cnt_lt(lo) < K <= cnt_lt(hi) ----
    unsigned loU = 0u, hiU = 0x7F800000u;   // [0, +inf)
    int cLo = 0, cHi = NN;
    float tPrev = t0; int cPrev = -1;
    int probes = 0;
    while (cHi - cLo > 64 && hiU - loU > 1u && probes < 34) {
        unsigned tU;
        if (probes == 0 && t0 > 0.f) {
            tU = __float_as_uint(t0);
        } else if (cPrev > 0 && probes < 8) {
            // local power law F(x) ~ x^2  ->  aim t' = t * sqrt(K/c)
            float g = tPrev * __fsqrt_rn((float)K / (float)cPrev);
            tU = __float_as_uint(g);
        } else if (cPrev == 0 && probes < 8) {
            tU = __float_as_uint(tPrev * 4.0f);
        } else {
            tU = loU + ((hiU - loU) >> 1);
        }
        if (tU <= loU || tU >= hiU) tU = loU + ((hiU - loU) >> 1);   // guaranteed shrink
        float t = __uint_as_float(tU);
        int c = 0;
        #pragma unroll
        for (int r = 0; r < 32; r++) c += (d2r[r] < t) ? 1 : 0;
        #pragma unroll
        for (int off = 1; off < 64; off <<= 1) c += __shfl_xor(c, off, 64);
        if (c >= K) { hiU = tU; cHi = c; } else { loU = tU; cLo = c; }
        tPrev = t; cPrev = c;
        probes++;
    }

    const float lo = __uint_as_float(loU);
    const float hi = __uint_as_float(hiU);
    const int  need = K - cLo;              // in [1, K]; window holds >= need values

    // ---- collect: v < lo -> selected (skip self); v in [lo, hi) -> candidates ----
    __builtin_amdgcn_wave_barrier();
    #pragma unroll 4
    for (int r = 0; r < 32; r++) {
        float v = d2r[r];
        int j = r * 64 + lane;
        if (v < lo) {
            if (j != i) {
                int m = atomicAdd(&selc[w], 1);
                if (m < 64) { isel[w][m] = j; wsel[w][m] = v; }   // store d2; exp later
            }
        } else if (v < hi) {
            int e = atomicAdd(&eqc[w], 1);
            if (e < 64) candk[w][e] = ((unsigned long long)__float_as_uint(v) << 32) | (unsigned)j;
        }
    }
    __builtin_amdgcn_wave_barrier();

    // ---- rank candidates by (value, index); append `need` smallest, skipping self ----
    {
        int e = eqc[w]; e = e > 64 ? 64 : e;
        unsigned long long mykey = ~0ull;
        if (lane < e) mykey = candk[w][lane];
        int mr = 0;
        for (int u = 0; u < e; u++) {        // ds_read_b64 broadcast, conflict-free
            unsigned long long k2 = candk[w][u];
            mr += (k2 < mykey) ? 1 : 0;
        }
        int mj = (int)(mykey & 0xFFFFFFFFull);
        if (lane < e && mr < need && mj != i) {
            int m = atomicAdd(&selc[w], 1);
            if (m < 64) { isel[w][m] = mj; wsel[w][m] = __uint_as_float((unsigned)(mykey >> 32)); }
        }
    }
    __builtin_amdgcn_wave_barrier();

    int nsel = selc[w]; nsel = nsel > 64 ? 64 : nsel;   // expect K-1 = 39
    if (lane < nsel) wsel[w][lane] = __expf(-wsel[w][lane]);
    __builtin_amdgcn_wave_barrier();

    // ---- weighted max / mean: lanes 0-21 do even m, lanes 32-53 odd m ----
    const float* fb = feats + (size_t)b * NN * PP;
    int g = lane >> 5, c = lane & 31;
    float mx = -INFINITY, sm = 0.f;
    if (c < PP) {
        for (int m = g; m < nsel; m += 2) {
            int j = isel[w][m]; float wt = wsel[w][m];
            float f = fb[(size_t)j * PP + c];
            float wf = wt * f;
            mx = fmaxf(mx, wf); sm += wf;
        }
    }
    float mx2 = __shfl_xor(mx, 32, 64);
    float sm2 = __shfl_xor(sm, 32, 64);
    mx = fmaxf(mx, mx2); sm += sm2;
    if (g == 0 && c < PP) {
        agg[(size_t)q * 44 + c]      = mx;
        agg[(size_t)q * 44 + PP + c] = sm / (float)(K - 1);
    }
}

// ---------------- Kernel 3: out = tanh([x | agg] @ Wo + bo) ----------------
__global__ __launch_bounds__(128) void out_kernel(
    const float* __restrict__ x, const float* __restrict__ agg,
    const float* __restrict__ Wo, const float* __restrict__ bo,
    float* __restrict__ out)
{
    __shared__ float sX[128 * 65];                   // stride 65: conflict-free column reads
    __shared__ float sA[128 * 45];                   // stride 45: gcd(45,32)=1
    __shared__ __align__(16) float sWo[FPDIM * 44];  // rows padded to 44 for float4 reads
    __shared__ float sbo[OO];

    const int t = threadIdx.x;
    const int rowBase = blockIdx.x * 128;

    {
        const float4* xg = (const float4*)(x + (size_t)rowBase * FF);
        #pragma unroll
        for (int it = 0; it < 16; it++) {            // 128*64/4 = 2048 float4
            int idx = it * 128 + t;
            float4 v = xg[idx];
            int row = idx >> 4, col = (idx & 15) << 2;
            float* p = &sX[row * 65 + col];
            p[0] = v.x; p[1] = v.y; p[2] = v.z; p[3] = v.w;
        }
        for (int it = 0; it < 44; it++) {            // 128*44 floats
            int idx = it * 128 + t;
            int row = idx / 44, col = idx - row * 44;
            sA[row * 45 + col] = agg[(size_t)rowBase * 44 + idx];
        }
        for (int it = 0; it < 36; it++) {            // 108*42 = 4536 floats
            int idx = it * 128 + t;
            if (idx < FPDIM * OO) {
                int row = idx / OO, col = idx - row * OO;
                sWo[row * 44 + col] = Wo[idx];
            }
        }
        if (t < OO) sbo[t] = bo[t];
    }
    __syncthreads();

    float acc[44];
    #pragma unroll
    for (int o = 0; o < 44; o++) acc[o] = (o < OO) ? sbo[o] : 0.f;

    const float* xr = &sX[t * 65];
    const float* ar = &sA[t * 45];
    for (int k = 0; k < FF; k++) {
        float u = xr[k];
        const float* wrow = &sWo[k * 44];
        #pragma unroll
        for (int o4 = 0; o4 < 11; o4++) {
            float4 wv = *((const float4*)&wrow[o4 * 4]);
            acc[o4*4+0] = fmaf(u, wv.x, acc[o4*4+0]);
            acc[o4*4+1] = fmaf(u, wv.y, acc[o4*4+1]);
            acc[o4*4+2] = fmaf(u, wv.z, acc[o4*4+2]);
            acc[o4*4+3] = fmaf(u, wv.w, acc[o4*4+3]);
        }
    }
    for (int k = 0; k < 2 * PP; k++) {
        float u = ar[k];
        const float* wrow = &sWo[(FF + k) * 44];
        #pragma unroll
        for (int o4 = 0; o4 < 11; o4++) {
            float4 wv = *((const float4*)&wrow[o4 * 4]);
            acc[o4*4+0] = fmaf(u, wv.x, acc[o4*4+0]);
            acc[o4*4+1] = fmaf(u, wv.y, acc[o4*4+1]);
            acc[o4*4+2] = fmaf(u, wv.z, acc[o4*4+2]);
            acc[o4*4+3] = fmaf(u, wv.w, acc[o4*4+3]);
        }
    }

    __syncthreads();                                  // done reading sA as input
    float* orow = &sA[t * 43];                        // reuse sA (stride 43, gcd(43,32)=1)
    #pragma unroll
    for (int o = 0; o < OO; o++) {
        float a = acc[o];
        a = a < -12.f ? -12.f : (a > 12.f ? 12.f : a);
        float e2 = __expf(2.f * a);
        orow[o] = (e2 - 1.f) / (e2 + 1.f);
    }
    __syncthreads();
    for (int it = 0; it < 42; it++) {                 // coalesced store of 128*42 floats
        int idx = it * 128 + t;
        int row = idx / 42, col = idx - row * 42;
        out[(size_t)rowBase * 42 + idx] = sA[row * 43 + col];
    }
}

extern "C" void kernel_launch(void* const* d_in, const int* in_sizes, int n_in,
                              void* d_out, int out_size, void* d_ws, size_t ws_size,
                              hipStream_t stream) {
    const float* x  = (const float*)d_in[0];
    const float* Ws = (const float*)d_in[1];
    const float* bs = (const float*)d_in[2];
    const float* Wf = (const float*)d_in[3];
    const float* bf = (const float*)d_in[4];
    const float* Wo = (const float*)d_in[5];
    const float* bo = (const float*)d_in[6];
    const int*   nn = (const int*)d_in[7];
    float* out = (float*)d_out;

    float* coords = (float*)d_ws;                              // 16*2048*4  = 512 KB
    float* feats  = coords + (size_t)BB * NN * SS;             // 16*2048*22 = 2.75 MB
    float* agg    = feats  + (size_t)BB * NN * PP;             // 32768*44   = 5.5 MB

    precompute_kernel<<<(BB * NN) / 256, 256, 0, stream>>>(x, Ws, bs, Wf, bf, coords, feats);
    knn_agg_kernel<<<(BB * NN) / 2, 128, 0, stream>>>(coords, feats, nn, agg);
    out_kernel<<<(BB * NN) / 128, 128, 0, stream>>>(x, agg, Wo, bo, out);
}

// Round 7
// 230.934 us; speedup vs baseline: 1.1966x; 1.1966x over previous
//
#include <hip/hip_runtime.h>
#include <math.h>

#define BB 16
#define NN 2048
#define FF 64
#define SS 4
#define PP 22
#define OO 42
#define FPDIM (FF + 2*PP)   // 108
#define NREG 24             // d2 values kept in VGPRs per lane
#define NLDS 8              // d2 values kept in LDS rows per lane (NREG+NLDS = 2048/64)

__device__ __forceinline__ float readfirstlane_f32(float v) {
    // value-preserving wave-uniform broadcast (builtin is int->int; must pass bits!)
    return __uint_as_float((unsigned)__builtin_amdgcn_readfirstlane((int)__float_as_uint(v)));
}

// ---------------- Kernel 1: coords = x@W_s + b_s ; feats = x@W_f + b_f ----------------
__global__ __launch_bounds__(256) void precompute_kernel(
    const float* __restrict__ x, const float* __restrict__ Ws, const float* __restrict__ bs,
    const float* __restrict__ Wf, const float* __restrict__ bf,
    float* __restrict__ coords, float* __restrict__ feats)
{
    int row = blockIdx.x * 256 + threadIdx.x;   // 0 .. B*N-1
    if (row >= BB * NN) return;

    const float4* x4 = (const float4*)(x + (size_t)row * FF);
    float c0 = bs[0], c1 = bs[1], c2 = bs[2], c3 = bs[3];
    float f[PP];
    #pragma unroll
    for (int c = 0; c < PP; c++) f[c] = bf[c];

    #pragma unroll
    for (int k4 = 0; k4 < FF / 4; k4++) {
        float4 xv = x4[k4];
        float xs[4] = {xv.x, xv.y, xv.z, xv.w};
        #pragma unroll
        for (int r = 0; r < 4; r++) {
            int k = k4 * 4 + r;
            float xk = xs[r];
            c0 = fmaf(xk, Ws[k * SS + 0], c0);
            c1 = fmaf(xk, Ws[k * SS + 1], c1);
            c2 = fmaf(xk, Ws[k * SS + 2], c2);
            c3 = fmaf(xk, Ws[k * SS + 3], c3);
            #pragma unroll
            for (int c = 0; c < PP; c++) f[c] = fmaf(xk, Wf[k * PP + c], f[c]);
        }
    }
    float4* cp = (float4*)(coords + (size_t)row * SS);
    *cp = make_float4(c0, c1, c2, c3);
    float* fo = feats + (size_t)row * PP;
    #pragma unroll
    for (int c = 0; c < PP; c++) fo[c] = f[c];
}

// ---------------- Kernel 2: wave-per-query kNN, counting bisection, ballot compaction ----------------
// (128,4): 4 blocks x 2 waves = 8 waves/EU -> 64-VGPR budget (R5 calibration: arg2 multiplies
// by waves-per-block). Live set trimmed to fit: 24 d2 in VGPRs + 8 rows in per-wave LDS.
__global__ __launch_bounds__(128, 4) void knn_agg_kernel(
    const float* __restrict__ coords, const float* __restrict__ feats,
    const int* __restrict__ nnbr, float* __restrict__ agg)
{
    const int lane = threadIdx.x & 63;
    const int w    = threadIdx.x >> 6;
    const int q    = blockIdx.x * 2 + w;       // 0..32767
    const int b    = q >> 11;
    const int i    = q & (NN - 1);

    int K = *nnbr; K = K < 2 ? 2 : (K > 64 ? 64 : K);

    __shared__ float d2x[2][NLDS * 64];           // 2 KB per wave
    __shared__ int   isel[2][64];
    __shared__ float wsel[2][64];
    __shared__ unsigned long long candk[2][64];   // (d2bits<<32)|j packed keys

    const float4* cb = (const float4*)(coords + (size_t)b * NN * SS);
    float4 qv = cb[i];
    // wave-uniform -> SGPRs via bit-pattern readfirstlane (value-preserving)
    const float qx = readfirstlane_f32(qv.x);
    const float qy = readfirstlane_f32(qv.y);
    const float qz = readfirstlane_f32(qv.z);
    const float qw = readfirstlane_f32(qv.w);

    // ---- distances: 24 in VGPRs, 8 rows in LDS; track per-lane min ----
    float d2r[NREG];
    float lmin = INFINITY;
    #pragma unroll
    for (int r = 0; r < NREG; r++) {
        float4 c = cb[r * 64 + lane];
        float d0 = qx - c.x, d1 = qy - c.y, d2 = qz - c.z, d3 = qw - c.w;
        float v = d0 * d0 + d1 * d1 + d2 * d2 + d3 * d3;
        d2r[r] = v;
        lmin = fminf(lmin, v);
    }
    #pragma unroll 2
    for (int r = NREG; r < 32; r++) {
        float4 c = cb[r * 64 + lane];
        float d0 = qx - c.x, d1 = qy - c.y, d2 = qz - c.z, d3 = qw - c.w;
        float v = d0 * d0 + d1 * d1 + d2 * d2 + d3 * d3;
        d2x[w][(r - NREG) * 64 + lane] = v;
        lmin = fminf(lmin, v);
    }
    __builtin_amdgcn_wave_barrier();

    // ---- first-probe estimator: mean of per-lane minima ~ K/N quantile ----
    float s = lmin;
    #pragma unroll
    for (int off = 1; off < 64; off <<= 1) s += __shfl_xor(s, off, 64);
    float t0 = s * (1.0f / 64.0f);

    // ---- bisection on the threshold: invariant cnt_lt(lo) < K <= cnt_lt(hi) ----
    unsigned loU = 0u, hiU = 0x7F800000u;   // [0, +inf)
    int cLo = 0, cHi = NN;
    float tPrev = t0; int cPrev = -1;
    int probes = 0;
    while (cHi - cLo > 64 && hiU - loU > 1u && probes < 34) {
        unsigned tU;
        if (probes == 0 && t0 > 0.f) {
            tU = __float_as_uint(t0);
        } else if (cPrev > 0 && probes < 8) {
            // local power law F(x) ~ x^2  ->  aim t' = t * sqrt(K/c)
            float g = tPrev * __fsqrt_rn((float)K / (float)cPrev);
            tU = __float_as_uint(g);
        } else if (cPrev == 0 && probes < 8) {
            tU = __float_as_uint(tPrev * 4.0f);
        } else {
            tU = loU + ((hiU - loU) >> 1);
        }
        if (tU <= loU || tU >= hiU) tU = loU + ((hiU - loU) >> 1);   // guaranteed shrink
        float t = __uint_as_float(tU);
        int c = 0;
        #pragma unroll
        for (int r = 0; r < NREG; r++) c += (d2r[r] < t) ? 1 : 0;
        #pragma unroll
        for (int r8 = 0; r8 < NLDS; r8++) c += (d2x[w][r8 * 64 + lane] < t) ? 1 : 0;
        #pragma unroll
        for (int off = 1; off < 64; off <<= 1) c += __shfl_xor(c, off, 64);
        if (c >= K) { hiU = tU; cHi = c; } else { loU = tU; cLo = c; }
        tPrev = t; cPrev = c;
        probes++;
    }

    const float lo = __uint_as_float(loU);
    const float hi = __uint_as_float(hiU);
    const int  need = K - cLo;              // in [1, K]; window holds >= need values

    // ---- collect via ballot compaction (no atomics): below -> isel/wsel, window -> candk ----
    int base = 0, ebase = 0;
    __builtin_amdgcn_wave_barrier();
    #pragma unroll
    for (int r = 0; r < 32; r++) {
        float v = (r < NREG) ? d2r[r] : d2x[w][(r - NREG) * 64 + lane];
        int j = r * 64 + lane;
        bool p1 = (v < lo) & (j != i);
        unsigned long long m1 = __ballot(p1);
        if (p1) {
            int slot = base + __popcll(m1 & ((1ull << lane) - 1ull));
            if (slot < 64) { isel[w][slot] = j; wsel[w][slot] = v; }
        }
        base += __popcll(m1);
        bool p2 = (v >= lo) & (v < hi);
        unsigned long long m2 = __ballot(p2);
        if (p2) {
            int slot = ebase + __popcll(m2 & ((1ull << lane) - 1ull));
            if (slot < 64) candk[w][slot] = ((unsigned long long)__float_as_uint(v) << 32) | (unsigned)j;
        }
        ebase += __popcll(m2);
    }
    __builtin_amdgcn_wave_barrier();

    // ---- rank candidates by (value, index); append `need` smallest, skipping self ----
    {
        int e = ebase > 64 ? 64 : ebase;
        unsigned long long mykey = ~0ull;
        if (lane < e) mykey = candk[w][lane];
        int mr = 0;
        for (int u = 0; u < e; u++) {        // ds_read_b64 broadcast, conflict-free
            unsigned long long k2 = candk[w][u];
            mr += (k2 < mykey) ? 1 : 0;
        }
        int mj = (int)(mykey & 0xFFFFFFFFull);
        bool ps = (lane < e) & (mr < need) & (mj != i);
        unsigned long long ms = __ballot(ps);
        if (ps) {
            int slot = base + __popcll(ms & ((1ull << lane) - 1ull));
            if (slot < 64) { isel[w][slot] = mj; wsel[w][slot] = __uint_as_float((unsigned)(mykey >> 32)); }
        }
        base += __popcll(ms);
    }
    __builtin_amdgcn_wave_barrier();

    int nsel = base > 64 ? 64 : base;       // expect K-1 = 39
    if (lane < nsel) wsel[w][lane] = __expf(-wsel[w][lane]);
    __builtin_amdgcn_wave_barrier();

    // ---- weighted max / mean: lanes 0-21 do even m, lanes 32-53 odd m ----
    const float* fb = feats + (size_t)b * NN * PP;
    int g = lane >> 5, c = lane & 31;
    float mx = -INFINITY, sm = 0.f;
    if (c < PP) {
        for (int m = g; m < nsel; m += 2) {
            int j = isel[w][m]; float wt = wsel[w][m];
            float f = fb[(size_t)j * PP + c];
            float wf = wt * f;
            mx = fmaxf(mx, wf); sm += wf;
        }
    }
    float mx2 = __shfl_xor(mx, 32, 64);
    float sm2 = __shfl_xor(sm, 32, 64);
    mx = fmaxf(mx, mx2); sm += sm2;
    if (g == 0 && c < PP) {
        agg[(size_t)q * 44 + c]      = mx;
        agg[(size_t)q * 44 + PP + c] = sm / (float)(K - 1);
    }
}

// ---------------- Kernel 3: out = tanh([x | agg] @ Wo + bo) ----------------
__global__ __launch_bounds__(128) void out_kernel(
    const float* __restrict__ x, const float* __restrict__ agg,
    const float* __restrict__ Wo, const float* __restrict__ bo,
    float* __restrict__ out)
{
    __shared__ float sX[128 * 65];                   // stride 65: conflict-free column reads
    __shared__ float sA[128 * 45];                   // stride 45: gcd(45,32)=1
    __shared__ __align__(16) float sWo[FPDIM * 44];  // rows padded to 44 for float4 reads
    __shared__ float sbo[OO];

    const int t = threadIdx.x;
    const int rowBase = blockIdx.x * 128;

    {
        const float4* xg = (const float4*)(x + (size_t)rowBase * FF);
        #pragma unroll
        for (int it = 0; it < 16; it++) {            // 128*64/4 = 2048 float4
            int idx = it * 128 + t;
            float4 v = xg[idx];
            int row = idx >> 4, col = (idx & 15) << 2;
            float* p = &sX[row * 65 + col];
            p[0] = v.x; p[1] = v.y; p[2] = v.z; p[3] = v.w;
        }
        for (int it = 0; it < 44; it++) {            // 128*44 floats
            int idx = it * 128 + t;
            int row = idx / 44, col = idx - row * 44;
            sA[row * 45 + col] = agg[(size_t)rowBase * 44 + idx];
        }
        for (int it = 0; it < 36; it++) {            // 108*42 = 4536 floats
            int idx = it * 128 + t;
            if (idx < FPDIM * OO) {
                int row = idx / OO, col = idx - row * OO;
                sWo[row * 44 + col] = Wo[idx];
            }
        }
        if (t < OO) sbo[t] = bo[t];
    }
    __syncthreads();

    float acc[44];
    #pragma unroll
    for (int o = 0; o < 44; o++) acc[o] = (o < OO) ? sbo[o] : 0.f;

    const float* xr = &sX[t * 65];
    const float* ar = &sA[t * 45];
    for (int k = 0; k < FF; k++) {
        float u = xr[k];
        const float* wrow = &sWo[k * 44];
        #pragma unroll
        for (int o4 = 0; o4 < 11; o4++) {
            float4 wv = *((const float4*)&wrow[o4 * 4]);
            acc[o4*4+0] = fmaf(u, wv.x, acc[o4*4+0]);
            acc[o4*4+1] = fmaf(u, wv.y, acc[o4*4+1]);
            acc[o4*4+2] = fmaf(u, wv.z, acc[o4*4+2]);
            acc[o4*4+3] = fmaf(u, wv.w, acc[o4*4+3]);
        }
    }
    for (int k = 0; k < 2 * PP; k++) {
        float u = ar[k];
        const float* wrow = &sWo[(FF + k) * 44];
        #pragma unroll
        for (int o4 = 0; o4 < 11; o4++) {
            float4 wv = *((const float4*)&wrow[o4 * 4]);
            acc[o4*4+0] = fmaf(u, wv.x, acc[o4*4+0]);
            acc[o4*4+1] = fmaf(u, wv.y, acc[o4*4+1]);
            acc[o4*4+2] = fmaf(u, wv.z, acc[o4*4+2]);
            acc[o4*4+3] = fmaf(u, wv.w, acc[o4*4+3]);
        }
    }

    __syncthreads();                                  // done reading sA as input
    float* orow = &sA[t * 43];                        // reuse sA (stride 43, gcd(43,32)=1)
    #pragma unroll
    for (int o = 0; o < OO; o++) {
        float a = acc[o];
        a = a < -12.f ? -12.f : (a > 12.f ? 12.f : a);
        float e2 = __expf(2.f * a);
        orow[o] = (e2 - 1.f) / (e2 + 1.f);
    }
    __syncthreads();
    for (int it = 0; it < 42; it++) {                 // coalesced store of 128*42 floats
        int idx = it * 128 + t;
        int row = idx / 42, col = idx - row * 42;
        out[(size_t)rowBase * 42 + idx] = sA[row * 43 + col];
    }
}

extern "C" void kernel_launch(void* const* d_in, const int* in_sizes, int n_in,
                              void* d_out, int out_size, void* d_ws, size_t ws_size,
                              hipStream_t stream) {
    const float* x  = (const float*)d_in[0];
    const float* Ws = (const float*)d_in[1];
    const float* bs = (const float*)d_in[2];
    const float* Wf = (const float*)d_in[3];
    const float* bf = (const float*)d_in[4];
    const float* Wo = (const float*)d_in[5];
    const float* bo = (const float*)d_in[6];
    const int*   nn = (const int*)d_in[7];
    float* out = (float*)d_out;

    float* coords = (float*)d_ws;                              // 16*2048*4  = 512 KB
    float* feats  = coords + (size_t)BB * NN * SS;             // 16*2048*22 = 2.75 MB
    float* agg    = feats  + (size_t)BB * NN * PP;             // 32768*44   = 5.5 MB

    precompute_kernel<<<(BB * NN) / 256, 256, 0, stream>>>(x, Ws, bs, Wf, bf, coords, feats);
    knn_agg_kernel<<<(BB * NN) / 2, 128, 0, stream>>>(coords, feats, nn, agg);
    out_kernel<<<(BB * NN) / 128, 128, 0, stream>>>(x, agg, Wo, bo, out);
}